// Round 1
// baseline (310.870 us; speedup 1.0000x reference)
//
#include <hip/hip_runtime.h>

#define DZ 96
#define HY 192
#define WX 192
#define SH (WX)          // stride along y
#define SD (HY*WX)       // stride along z
#define NTOT (DZ*HY*WX)  // 3538944
#define DTc 0.01f
#define REc 0.001f

struct S7 { float c,xm,xp,ym,yp,zm,zp; };

__device__ __forceinline__ S7 ld7(const float* __restrict__ f, int idx, int x,int y,int z){
  S7 s;
  s.c  = f[idx];
  s.xm = (x>0)    ? f[idx-1]  : 0.f;
  s.xp = (x<WX-1) ? f[idx+1]  : 0.f;
  s.ym = (y>0)    ? f[idx-SH] : 0.f;
  s.yp = (y<HY-1) ? f[idx+SH] : 0.f;
  s.zm = (z>0)    ? f[idx-SD] : 0.f;
  s.zp = (z<DZ-1) ? f[idx+SD] : 0.f;
  return s;
}
__device__ __forceinline__ float lap7(const S7& s){ return s.xm+s.xp+s.ym+s.yp+s.zm+s.zp - 6.f*s.c; }
__device__ __forceinline__ float ddx(const S7& s){ return 0.5f*(s.xp-s.xm); }
__device__ __forceinline__ float ddy(const S7& s){ return 0.5f*(s.yp-s.ym); }
__device__ __forceinline__ float ddz(const S7& s){ return 0.5f*(s.zp-s.zm); }

// K0: damping + inv field
__global__ void k0_damp(const float* __restrict__ vu, const float* __restrict__ vv,
                        const float* __restrict__ vw, const float* __restrict__ sig,
                        float* __restrict__ u, float* __restrict__ v,
                        float* __restrict__ w, float* __restrict__ inv){
  int idx = blockIdx.x*blockDim.x + threadIdx.x;
  if (idx >= NTOT) return;
  float iv = 1.0f / (1.0f + DTc * sig[idx]);
  inv[idx] = iv;
  u[idx] = vu[idx]*iv;
  v[idx] = vv[idx]*iv;
  w[idx] = vw[idx]*iv;
}

// K1: predictor -> b_u, b_v, b_w
__global__ void k1_pred(const float* __restrict__ u0, const float* __restrict__ v0,
                        const float* __restrict__ w0, const float* __restrict__ p,
                        const float* __restrict__ inv,
                        float* __restrict__ bu, float* __restrict__ bv, float* __restrict__ bw){
  int x = blockIdx.x*blockDim.x + threadIdx.x;
  int y = blockIdx.y*blockDim.y + threadIdx.y;
  int z = blockIdx.z;
  int idx = (z*HY + y)*WX + x;
  S7 su = ld7(u0,idx,x,y,z), sv = ld7(v0,idx,x,y,z), sw = ld7(w0,idx,x,y,z);
  float pxm = (x>0)?p[idx-1]:0.f,  pxp=(x<WX-1)?p[idx+1]:0.f;
  float pym = (y>0)?p[idx-SH]:0.f, pyp=(y<HY-1)?p[idx+SH]:0.f;
  float pzm = (z>0)?p[idx-SD]:0.f, pzp=(z<DZ-1)?p[idx+SD]:0.f;
  float m = (float)((x==0)+(x==WX-1)+(y==0)+(y==HY-1)+(z==0)+(z==DZ-1));
  float iv = inv[idx];
  float uc=su.c, vc=sv.c, wc=sw.c;
  float ku = lap7(su) + 0.5f*m*uc;
  float kv = lap7(sv) + 0.5f*m*vc;
  float kw = lap7(sw) + 0.5f*m*wc;
  float bu_ = uc + 0.5f*(REc*ku*DTc - uc*ddx(su)*DTc - vc*ddy(su)*DTc - wc*ddz(su)*DTc) - 0.5f*(pxp-pxm)*DTc;
  float bv_ = vc + 0.5f*(REc*kv*DTc - uc*ddx(sv)*DTc - vc*ddy(sv)*DTc - wc*ddz(sv)*DTc) - 0.5f*(pyp-pym)*DTc;
  float bw_ = wc + 0.5f*(REc*kw*DTc - uc*ddx(sw)*DTc - vc*ddy(sw)*DTc - wc*ddz(sw)*DTc) - 0.5f*(pzp-pzm)*DTc;
  bu[idx] = bu_*iv; bv[idx] = bv_*iv; bw[idx] = bw_*iv;
}

// K2: corrector -> u1,v1,w1 (in-place over u0,v0,w0: only center of u/v/w read)
__global__ void k2_corr(const float* __restrict__ bu, const float* __restrict__ bv,
                        const float* __restrict__ bw, const float* __restrict__ p,
                        const float* __restrict__ inv,
                        float* __restrict__ u, float* __restrict__ v, float* __restrict__ w){
  int x = blockIdx.x*blockDim.x + threadIdx.x;
  int y = blockIdx.y*blockDim.y + threadIdx.y;
  int z = blockIdx.z;
  int idx = (z*HY + y)*WX + x;
  S7 sbu = ld7(bu,idx,x,y,z), sbv = ld7(bv,idx,x,y,z), sbw = ld7(bw,idx,x,y,z);
  float pxm = (x>0)?p[idx-1]:0.f,  pxp=(x<WX-1)?p[idx+1]:0.f;
  float pym = (y>0)?p[idx-SH]:0.f, pyp=(y<HY-1)?p[idx+SH]:0.f;
  float pzm = (z>0)?p[idx-SD]:0.f, pzp=(z<DZ-1)?p[idx+SD]:0.f;
  float m = (float)((x==0)+(x==WX-1)+(y==0)+(y==HY-1)+(z==0)+(z==DZ-1));
  float iv = inv[idx];
  float buc=sbu.c, bvc=sbv.c, bwc=sbw.c;
  float ku = lap7(sbu) + 0.5f*m*buc;
  float kv = lap7(sbv) + 0.5f*m*bvc;
  float kw = lap7(sbw) + 0.5f*m*bwc;
  float u1 = u[idx] + REc*ku*DTc - buc*ddx(sbu)*DTc - bvc*ddy(sbu)*DTc - bwc*ddz(sbu)*DTc - 0.5f*(pxp-pxm)*DTc;
  float v1 = v[idx] + REc*kv*DTc - buc*ddx(sbv)*DTc - bvc*ddy(sbv)*DTc - bwc*ddz(sbv)*DTc - 0.5f*(pyp-pym)*DTc;
  float w1 = w[idx] + REc*kw*DTc - buc*ddx(sbw)*DTc - bvc*ddy(sbw)*DTc - bwc*ddz(sbw)*DTc - 0.5f*(pzp-pzm)*DTc;
  u[idx] = u1*iv; v[idx] = v1*iv; w[idx] = w1*iv;
}

// K3: divergence source b = -(du/dx + dv/dy + dw/dz)/DT
__global__ void k3_div(const float* __restrict__ u, const float* __restrict__ v,
                       const float* __restrict__ w, float* __restrict__ bdiv){
  int x = blockIdx.x*blockDim.x + threadIdx.x;
  int y = blockIdx.y*blockDim.y + threadIdx.y;
  int z = blockIdx.z;
  int idx = (z*HY + y)*WX + x;
  float dux = 0.5f*(((x<WX-1)?u[idx+1]:0.f)  - ((x>0)?u[idx-1]:0.f));
  float dvy = 0.5f*(((y<HY-1)?v[idx+SH]:0.f) - ((y>0)?v[idx-SH]:0.f));
  float dwz = 0.5f*(((z<DZ-1)?w[idx+SD]:0.f) - ((z>0)?w[idx-SD]:0.f));
  bdiv[idx] = -(dux+dvy+dwz)/DTc;
}

// K4: residual r0 = A(p) - b
__global__ void k4_res(const float* __restrict__ p, const float* __restrict__ b,
                       float* __restrict__ r0){
  int x = blockIdx.x*blockDim.x + threadIdx.x;
  int y = blockIdx.y*blockDim.y + threadIdx.y;
  int z = blockIdx.z;
  int idx = (z*HY + y)*WX + x;
  S7 sp = ld7(p,idx,x,y,z);
  r0[idx] = lap7(sp) - b[idx];
}

// restrict: coarse = mean of 2x2x2 fine cells
__global__ void k_restrict(const float* __restrict__ fine, float* __restrict__ coarse,
                           int cD,int cH,int cW){
  int n = cD*cH*cW;
  int idx = blockIdx.x*blockDim.x + threadIdx.x;
  if (idx>=n) return;
  int x = idx % cW; int t = idx / cW; int y = t % cH; int z = t / cH;
  int fW = cW*2, fH = cH*2;
  int sdf = fH*fW;
  int fi = ((2*z)*fH + 2*y)*fW + 2*x;
  float s = fine[fi] + fine[fi+1] + fine[fi+fW] + fine[fi+fW+1]
          + fine[fi+sdf] + fine[fi+sdf+1] + fine[fi+sdf+fW] + fine[fi+sdf+fW+1];
  coarse[idx] = 0.125f*s;
}

// last restrict (r2 -> r3 @ 12x24x24) fused with coarsest Jacobi: w3 = r3/diag
__global__ void k_restrict_coarse(const float* __restrict__ fine, float* __restrict__ r3,
                                  float* __restrict__ w3){
  const int cD=12,cH=24,cW=24;
  int n = cD*cH*cW;
  int idx = blockIdx.x*blockDim.x + threadIdx.x;
  if (idx>=n) return;
  int x = idx % cW; int t = idx / cW; int y = t % cH; int z = t / cH;
  int fW = cW*2, fH = cH*2;
  int sdf = fH*fW;
  int fi = ((2*z)*fH + 2*y)*fW + 2*x;
  float s = fine[fi] + fine[fi+1] + fine[fi+fW] + fine[fi+fW+1]
          + fine[fi+sdf] + fine[fi+sdf+1] + fine[fi+sdf+fW] + fine[fi+sdf+fW+1];
  float val = 0.125f*s;
  r3[idx] = val;
  w3[idx] = val / -6.0f;
}

// Jacobi smooth at level L with prolonged coarse correction:
// w = t - A(pad(t))/diag + r/diag,  t = prol(w_coarse), diag = -6
__global__ void k_jacobi(const float* __restrict__ wc, const float* __restrict__ r,
                         float* __restrict__ wout, int lD,int lH,int lW){
  int n = lD*lH*lW;
  int idx = blockIdx.x*blockDim.x + threadIdx.x;
  if (idx>=n) return;
  int x = idx % lW; int t = idx/lW; int y = t % lH; int z = t/lH;
  int cW=lW>>1, cH=lH>>1;
  #define WCAT(zz,yy,xx) wc[(((zz)>>1)*cH + ((yy)>>1))*cW + ((xx)>>1)]
  float tc  = WCAT(z,y,x);
  float txm = (x>0)    ? WCAT(z,y,x-1) : 0.f;
  float txp = (x<lW-1) ? WCAT(z,y,x+1) : 0.f;
  float tym = (y>0)    ? WCAT(z,y-1,x) : 0.f;
  float typ = (y<lH-1) ? WCAT(z,y+1,x) : 0.f;
  float tzm = (z>0)    ? WCAT(z-1,y,x) : 0.f;
  float tzp = (z<lD-1) ? WCAT(z+1,y,x) : 0.f;
  #undef WCAT
  float lapt = txm+txp+tym+typ+tzm+tzp - 6.f*tc;
  wout[idx] = tc - lapt/(-6.0f) + r[idx]/(-6.0f);
}

// p update: p_new = p - prol(w1) + r0/6   (== p - wmg - A(p)/diag + b/diag)
__global__ void k_pup(const float* __restrict__ pin, const float* __restrict__ r0,
                      const float* __restrict__ w1, float* __restrict__ pout,
                      float* __restrict__ wmg_out, int write_wmg){
  int x = blockIdx.x*blockDim.x + threadIdx.x;
  int y = blockIdx.y*blockDim.y + threadIdx.y;
  int z = blockIdx.z;
  int idx = (z*HY + y)*WX + x;
  int cidx = ((z>>1)*(HY/2) + (y>>1))*(WX/2) + (x>>1);
  float wm = w1[cidx];
  pout[idx] = pin[idx] - wm + r0[idx]/6.0f;
  if (write_wmg) wmg_out[idx] = wm;
}

// final projection
__global__ void k_final(const float* __restrict__ u, const float* __restrict__ v,
                        const float* __restrict__ w, const float* __restrict__ p,
                        const float* __restrict__ inv,
                        float* __restrict__ uo, float* __restrict__ vo, float* __restrict__ wo){
  int x = blockIdx.x*blockDim.x + threadIdx.x;
  int y = blockIdx.y*blockDim.y + threadIdx.y;
  int z = blockIdx.z;
  int idx = (z*HY + y)*WX + x;
  float dpx = 0.5f*(((x<WX-1)?p[idx+1]:0.f)  - ((x>0)?p[idx-1]:0.f));
  float dpy = 0.5f*(((y<HY-1)?p[idx+SH]:0.f) - ((y>0)?p[idx-SH]:0.f));
  float dpz = 0.5f*(((z<DZ-1)?p[idx+SD]:0.f) - ((z>0)?p[idx-SD]:0.f));
  float iv = inv[idx];
  uo[idx] = (u[idx] - dpx*DTc)*iv;
  vo[idx] = (v[idx] - dpy*DTc)*iv;
  wo[idx] = (w[idx] - dpz*DTc)*iv;
}

extern "C" void kernel_launch(void* const* d_in, const int* in_sizes, int n_in,
                              void* d_out, int out_size, void* d_ws, size_t ws_size,
                              hipStream_t stream){
  const float* vu  = (const float*)d_in[0];
  const float* vv  = (const float*)d_in[1];
  const float* vw  = (const float*)d_in[2];
  const float* vp  = (const float*)d_in[3];
  const float* sig = (const float*)d_in[4];
  // d_in[5..10] stencil weights (hardcoded), d_in[11] iteration (fixed = 2)

  const size_t N = (size_t)NTOT;
  float* ws  = (float*)d_ws;
  float* u   = ws;         // u0 -> u1
  float* v   = ws + N;
  float* w   = ws + 2*N;
  float* inv = ws + 3*N;
  float* bu  = ws + 4*N;   // later bdiv
  float* bv  = ws + 5*N;   // later r0
  float* bw  = ws + 6*N;   // later p1
  float* r1  = ws + 7*N;            // 48*96*96 = 442368
  float* r2  = r1 + 442368;         // 24*48*48 = 55296
  float* w3  = r2 + 55296;          // 12*24*24 = 6912
  float* w2  = w3 + 6912;           // 55296
  float* w1  = w2 + 55296;          // 442368

  float* out     = (float*)d_out;
  float* out_u   = out;
  float* out_v   = out + N;
  float* out_w   = out + 2*N;
  float* out_p   = out + 3*N;
  float* out_wmg = out + 4*N;
  float* out_r   = out + 5*N;  // 6912 elements

  dim3 b3(64,4,1), g3(WX/64, HY/4, DZ);

  k0_damp<<<(NTOT+255)/256, 256, 0, stream>>>(vu,vv,vw,sig,u,v,w,inv);
  k1_pred<<<g3,b3,0,stream>>>(u,v,w,vp,inv,bu,bv,bw);
  k2_corr<<<g3,b3,0,stream>>>(bu,bv,bw,vp,inv,u,v,w);
  float* bdiv = bu; float* r0 = bv; float* p1 = bw;
  k3_div<<<g3,b3,0,stream>>>(u,v,w,bdiv);

  for (int it = 0; it < 2; ++it){
    const float* pin = (it==0) ? vp : p1;
    float* pout      = (it==0) ? p1 : out_p;
    int wflag        = (it==1) ? 1 : 0;
    k4_res<<<g3,b3,0,stream>>>(pin, bdiv, r0);
    k_restrict<<<(442368+255)/256,256,0,stream>>>(r0, r1, 48,96,96);
    k_restrict<<<(55296+255)/256,256,0,stream>>>(r1, r2, 24,48,48);
    k_restrict_coarse<<<(6912+255)/256,256,0,stream>>>(r2, out_r, w3);
    k_jacobi<<<(55296+255)/256,256,0,stream>>>(w3, r2, w2, 24,48,48);
    k_jacobi<<<(442368+255)/256,256,0,stream>>>(w2, r1, w1, 48,96,96);
    k_pup<<<g3,b3,0,stream>>>(pin, r0, w1, pout, out_wmg, wflag);
  }

  k_final<<<g3,b3,0,stream>>>(u,v,w,out_p,inv,out_u,out_v,out_w);
}